// Round 6
// baseline (178.644 us; speedup 1.0000x reference)
//
#include <hip/hip_runtime.h>

// Net: x[B,2] -> fc1(2->9)+ELU -> 19 x (9->9)+ELU -> fc21(9->2) -> log_softmax
// B = 2097152. Round 16: R15 base (NCH=4, BLK=64, lb(64,4), 88.4us) with ONE
// lever: the packed f16 exp-pair (2 trans + pack, ~29 cyc issue) is replaced
// by a 10-op packed-VALU exp2 (~20 cyc, zero trans).  Evidence: issue-cycle
// fit across R10/R14/R15 puts v_exp_f16 at ~13 cyc issue-occupancy (quarter
// -rate wave64); 960 trans/wave ~ 60% of the issue budget.  e2 keeps its
// single trans (poly on a lone value is not cheaper).
//
// Packed exp2(t), t in [-14, 0] (clamped; abs err <= 2^-14, negligible):
//   u  = t + 1536          (f16 RNE -> u = 1536 + r, r = round(t); exact:
//                           1519..1536 all have ulp=1 in f16)
//   r  = u - 1536; f = t - r in [-0.5, 0.5]  (Sterbenz-exact)
//   q  = 1 + f*(C1 + f*(C2 + f*C3))          (3x v_pk_fma_f16, ~1e-3 rel)
//   bits(u) = 0x6600 + r  ->  2^r = bits((bits(u) + 0x9A0F) << 10)
//                           (v_pk_add_u16 / v_pk_lshlrev_b16: per-half, no
//                            cross-half carry; r+15 in [1,15] -> normal f16)
//   e  = 2^r * q
//
// MFMA 16x16x32 f16 layouts:
//   C/D: lane L holds rows (L>>4)*4+reg        of col (L&15)   [4 f32]
//   B:   lane L holds k  = (L>>4)*8+j (j=0..7) of col (L&15)   [8 f16]
// u[0]=j0,1 relu(d0,d1); u[1]=j2,3 [relu(d2), 1.0h]; u[2]=j4,5 e(d0),e(d1);
// u[3]=j6,7 [e(d2), 1.0h-dead].  Bias col 27 (g3 j3); e2m cols k=8g+4..6.
// Neurons at rows {0,1,2,4,5,6,8,9,10} (p(i)=i+i/3) -> D reg 3 always +0.0
// -> 3 exps/lane/layer; rows 12..15 zero.
//
// ELU identity: ELU(z) = relu(z) + exp2(min(L*z,0)) - 1 (L=log2e); scales and
// the -1 folded into next layer's weights/bias in build_frags.

typedef _Float16 half8 __attribute__((ext_vector_type(8)));
typedef _Float16 h2 __attribute__((ext_vector_type(2)));
typedef unsigned short us2 __attribute__((ext_vector_type(2)));
typedef float float4v __attribute__((ext_vector_type(4)));
typedef unsigned int uint4v __attribute__((ext_vector_type(4)));

extern "C" __device__ _Float16 __ocml_exp2_f16(_Float16);

constexpr int H   = 9;
constexpr int NL  = 21;    // fc1 + 19 mid + fc21
constexpr int TPW = 16;    // batch tiles (of 16 rows) per wave
constexpr int NCH = 4;     // chains in flight per pass
constexpr int NPS = TPW / NCH;   // 4 passes
constexpr int BLK = 64;    // single-wave workgroups

__global__ void build_frags(const float* __restrict__ W1, const float* __restrict__ b1,
                            const float* __restrict__ Wmid, const float* __restrict__ bmid,
                            const float* __restrict__ W21, const float* __restrict__ b21,
                            _Float16* __restrict__ ws) {
    const float L   = 1.4426950408889634f;   // log2(e)
    const float LN2 = 0.6931471805599453f;
    int l    = blockIdx.x;      // 0..20
    int lane = threadIdx.x;     // 0..63
    int row  = lane & 15;       // A row
    int g    = lane >> 4;       // k group
    bool orow = ((row & 3) != 3) && (row < 12);   // rows {0,1,2,4,5,6,8,9,10}
    int  o    = row - (row >> 2);                 // neuron index at this row
    for (int j = 0; j < 8; ++j) {
        int k = g * 8 + j;
        float v = 0.0f;
        if (l == 0) {
            if (orow && k < 2)        v = L * W1[o * 2 + k];
            else if (orow && k == 27) v = L * b1[o];
        } else if (l <= 19) {
            const float* W = Wmid + (l - 1) * 81;
            const float* b = bmid + (l - 1) * 9;
            if (orow) {
                if (j < 3 && g < 3) {                    // relu slot
                    int r_in = g * 4 + j;
                    int i = r_in - (r_in >> 2);
                    v = W[o * 9 + i];
                } else if (j >= 4 && j < 7 && g < 3) {   // e2m slot
                    int r_in = g * 4 + (j - 4);
                    int i = r_in - (r_in >> 2);
                    v = L * W[o * 9 + i];
                } else if (k == 27) {                    // bias slot (g3 j3)
                    float s = 0.0f;
                    for (int i = 0; i < H; ++i) s += W[o * 9 + i];
                    v = L * (b[o] - s);
                }
            }
        } else {  // l == 20: logits at rows 0,1
            if (row < 2) {
                if (j < 3 && g < 3) {
                    int r_in = g * 4 + j;
                    int i = r_in - (r_in >> 2);
                    v = LN2 * W21[row * 9 + i];
                } else if (j >= 4 && j < 7 && g < 3) {
                    int r_in = g * 4 + (j - 4);
                    int i = r_in - (r_in >> 2);
                    v = W21[row * 9 + i];
                } else if (k == 27) {
                    float s = 0.0f;
                    for (int i = 0; i < H; ++i) s += W21[row * 9 + i];
                    v = b21[row] - s;
                }
            }
        }
        ws[l * 512 + lane * 8 + j] = (_Float16)v;
    }
}

// d (4 f32, d[3]==+0) -> next-layer B fragment.
// 16 regular VALU (full-rate) + 1 trans, vs R10/R15's 10 regular + 3 trans.
__device__ __forceinline__ half8 act_to_b(float4v d) {
    const h2 Z    = {(_Float16)0.f, (_Float16)0.f};
    const h2 CLMP = {(_Float16)-14.f, (_Float16)-14.f};
    const h2 MAGC = {(_Float16)1536.f, (_Float16)1536.f};
    const h2 C3   = {(_Float16)0.05550411f, (_Float16)0.05550411f};
    const h2 C2   = {(_Float16)0.24022651f, (_Float16)0.24022651f};
    const h2 C1   = {(_Float16)0.69314718f, (_Float16)0.69314718f};
    const h2 ONE  = {(_Float16)1.f, (_Float16)1.f};
    h2 p01 = __builtin_bit_cast(h2, __builtin_amdgcn_cvt_pkrtz(d[0], d[1]));
    h2 p2b = __builtin_bit_cast(h2, __builtin_amdgcn_cvt_pkrtz(d[2], 1.0f));
    h2 r01 = __builtin_elementwise_max(p01, Z);
    h2 r2b = __builtin_elementwise_max(p2b, Z);   // [relu(d2), 1.0h bias]
    h2 t01 = __builtin_elementwise_min(p01, Z);
    h2 t2b = __builtin_elementwise_min(p2b, Z);   // [min(d2,0), 0]
    // --- packed exp2(t01) on the full-rate VALU pipe ---
    h2 tc = __builtin_elementwise_max(t01, CLMP);
    h2 uu = tc + MAGC;                  // 1536 + round(tc)   (RNE, exact)
    h2 rr = uu - MAGC;                  // round(tc)
    h2 ff = tc - rr;                    // frac in [-0.5, 0.5] (exact)
    h2 qq = __builtin_elementwise_fma(ff, C3, C2);
    qq = __builtin_elementwise_fma(ff, qq, C1);
    qq = __builtin_elementwise_fma(ff, qq, ONE);
    us2 sb = (__builtin_bit_cast(us2, uu) +
              (us2){(unsigned short)0x9A0F, (unsigned short)0x9A0F})
             << (us2){(unsigned short)10, (unsigned short)10};
    h2 e01 = __builtin_bit_cast(h2, sb) * qq;     // 2^r * q
    // --- e2 keeps the single trans op (cheapest for a lone value) ---
    _Float16 e2 = __ocml_exp2_f16(t2b[0]);
    uint4v u;
    u[0] = __builtin_bit_cast(unsigned, r01);
    u[1] = __builtin_bit_cast(unsigned, r2b);
    u[2] = __builtin_bit_cast(unsigned, e01);
    u[3] = 0x3C000000u |                          // finite dead j7
           (unsigned)__builtin_bit_cast(unsigned short, e2);
    return __builtin_bit_cast(half8, u);
}

__device__ __forceinline__ float bperm(int byte_idx, float v) {
    return __builtin_bit_cast(float,
        __builtin_amdgcn_ds_bpermute(byte_idx, __builtin_bit_cast(int, v)));
}

// Wave-batched log-softmax + store for 4 tiles (dd[0..3] -> tiles gbase..+3).
__device__ __forceinline__ void softmax4(const float4v* dd, int gbase,
                                         int lane, int grp,
                                         float* __restrict__ out) {
    const float NLOG2E = -1.4426950408889634f;
    const float LN2f   = 0.6931471805599453f;
    const int bidx = (lane & 15) << 2;
    float a0 = bperm(bidx, dd[0][0]), a1 = bperm(bidx, dd[0][1]);
    float b0 = bperm(bidx, dd[1][0]), b1 = bperm(bidx, dd[1][1]);
    float c0 = bperm(bidx, dd[2][0]), c1 = bperm(bidx, dd[2][1]);
    float d0 = bperm(bidx, dd[3][0]), d1 = bperm(bidx, dd[3][1]);
    float l0 = (grp == 0) ? a0 : (grp == 1) ? b0 : (grp == 2) ? c0 : d0;
    float l1 = (grp == 0) ? a1 : (grp == 1) ? b1 : (grp == 2) ? c1 : d1;
    float mx  = fmaxf(l0, l1);
    float ad  = fabsf(l0 - l1);
    float e   = __builtin_amdgcn_exp2f(NLOG2E * ad);
    float lg  = __builtin_amdgcn_logf(1.0f + e);     // log2(1+e)
    float lse = fmaf(LN2f, lg, mx);
    ((float2*)out)[(gbase << 4) + lane] = make_float2(l0 - lse, l1 - lse);
}

__global__ __launch_bounds__(BLK, 4) void mlp_mfma(const float* __restrict__ x,
                                                   const _Float16* __restrict__ ws,
                                                   float* __restrict__ out) {
    const int lane  = threadIdx.x;        // single wave per block
    const int grp   = lane >> 4;
    const int col   = lane & 15;
    const int tile0 = blockIdx.x * TPW;   // < 131072, 32-bit safe

    const half8* wsv = (const half8*)ws;
    const unsigned bias_u1 = (grp == 3) ? 0x3C000000u : 0u;  // 1.0h @ j3 (k=27)
    const float4v ZV = {0.f, 0.f, 0.f, 0.f};

    // Load + pre-pack ALL 16 x fragments at wave start (1 VGPR each).
    // No g0 mask: layer-0 A cols k=8g,8g+1 are zero for g>0; x finite
    // (proven safe in R12/R14, both absmax 0.0).
    unsigned xb[TPW];
    #pragma unroll
    for (int k = 0; k < TPW; ++k) {
        float2 xv = ((const float2*)x)[((tile0 + k) << 4) + col];
        xb[k] = __builtin_bit_cast(unsigned,
                    __builtin_amdgcn_cvt_pkrtz(xv.x, xv.y));
    }

    #pragma unroll
    for (int pass = 0; pass < NPS; ++pass) {
        half8 bf[NCH];
        #pragma unroll
        for (int k = 0; k < NCH; ++k) {
            uint4v u;
            u[0] = xb[pass * NCH + k];
            u[1] = bias_u1;
            u[2] = 0u; u[3] = 0u;
            bf[k] = __builtin_bit_cast(half8, u);
        }

        // 21-layer chain, NCH independent chains in flight.
        float4v dd[NCH];
        #pragma unroll
        for (int l = 0; l < NL; ++l) {
            half8 A = wsv[l * 64 + lane];
            #pragma unroll
            for (int k = 0; k < NCH; ++k)
                dd[k] = __builtin_amdgcn_mfma_f32_16x16x32_f16(A, bf[k], ZV, 0, 0, 0);
            if (l < NL - 1) {
                #pragma unroll
                for (int k = 0; k < NCH; ++k)
                    bf[k] = act_to_b(dd[k]);
            }
        }

        softmax4(dd, tile0 + pass * NCH, lane, grp, out);
    }
}

extern "C" void kernel_launch(void* const* d_in, const int* in_sizes, int n_in,
                              void* d_out, int out_size, void* d_ws, size_t ws_size,
                              hipStream_t stream) {
    const float* x    = (const float*)d_in[0];
    const float* W1   = (const float*)d_in[1];
    const float* b1   = (const float*)d_in[2];
    const float* Wmid = (const float*)d_in[3];
    const float* bmid = (const float*)d_in[4];
    const float* W21  = (const float*)d_in[5];
    const float* b21  = (const float*)d_in[6];
    float* out = (float*)d_out;
    _Float16* ws = (_Float16*)d_ws;   // 21*512 halves = 21.5 KB

    build_frags<<<NL, 64, 0, stream>>>(W1, b1, Wmid, bmid, W21, b21, ws);

    const int nrows = in_sizes[0] / 2;           // 2097152
    const int tiles = nrows / 16;                // 131072
    const int blocks = tiles / TPW;              // 8192 single-wave blocks
    mlp_mfma<<<blocks, BLK, 0, stream>>>(x, ws, out);
}

// Round 9
// 158.476 us; speedup vs baseline: 1.1273x; 1.1273x over previous
//
#include <hip/hip_runtime.h>

// Net: x[B,2] -> fc1(2->9)+ELU -> 19 x (9->9)+ELU -> fc21(9->2) -> log_softmax
// B = 2097152. Round 19: R18 fused-slot reformulation, fixed builtin name
// (__builtin_amdgcn_mfma_f32_16x16x16f16 -- legacy shapes have no underscore
// before f16 on gfx950).  One B-slot per neuron instead of two:
//   s = ln2*relu(d) + exp2(min(d,0)) = relu(z) + e^min(z,0)   (d = L*z)
// carries a uniform scale, so the relu/exp slot split (K=28) collapses to
// K=16 and the MFMA shrinks 16x16x32 -> 16x16x16 (2-reg A/B, ~half the
// matrix-pipe cycles).  The rescale rides the existing add as v_pk_fma_f16.
// The -1 of ELU still folds into the next layer's bias: L*(b - sum W).
// act: 12 emitted (was 13), no zext/or; B-frag 2 VGPRs (was 4); A 2 (was 4).
// R17 lesson: MFMA via inline asm NaNs (no hazard nops) -- intrinsics only.
//
// MFMA 16x16x16 f16 layouts (same family as 16x16x32, K groups of 4):
//   C/D: lane L holds rows (L>>4)*4+reg      of col (L&15)   [4 f32]
//   A/B: lane L holds k = (L>>4)*4+j (j=0..3) of row/col (L&15) [4 f16]
// w0 = j0,1: s(d0), s(d1); w1 = j2,3: [s(d2), 1.0h].
// k-slot for input neuron i at k = p(i) = i + i/3 (k in {0,1,2,4,5,6,8,9,10});
// bias at k=15 (g3 j3, act emits constant 1.0h there); k=3,7,11,12..14 dead
// (zero A-columns, finite B values).  D rows {0,1,2,4,5,6,8,9,10} as before;
// D reg 3 always +0.0 -> 3 activations/lane/layer.
//
// Weights (build_frags): fc1 k<2: L*W1; mid: L*W (one slot per input);
// fc21: W21 plain; bias: L*b1 / L*(b - sum W) / (b21 - sum W21) -- identical
// formulas to the 2-slot scheme, only slot positions changed.

typedef _Float16 half4v __attribute__((ext_vector_type(4)));
typedef _Float16 h2 __attribute__((ext_vector_type(2)));
typedef float float4v __attribute__((ext_vector_type(4)));
typedef unsigned int uint2v __attribute__((ext_vector_type(2)));

constexpr int H   = 9;
constexpr int NL  = 21;    // fc1 + 19 mid + fc21
constexpr int TPW = 16;    // batch tiles (of 16 rows) per wave
constexpr int NCH = 4;     // chains in flight per pass
constexpr int NPS = TPW / NCH;   // 4 passes
constexpr int BLK = 64;    // single-wave workgroups

__global__ void build_frags(const float* __restrict__ W1, const float* __restrict__ b1,
                            const float* __restrict__ Wmid, const float* __restrict__ bmid,
                            const float* __restrict__ W21, const float* __restrict__ b21,
                            _Float16* __restrict__ ws) {
    const float L = 1.4426950408889634f;   // log2(e)
    int l    = blockIdx.x;      // 0..20
    int lane = threadIdx.x;     // 0..63
    int row  = lane & 15;       // A row (output neuron slot)
    int g    = lane >> 4;       // k group
    bool orow = ((row & 3) != 3) && (row < 12);   // rows {0,1,2,4,5,6,8,9,10}
    int  o    = row - (row >> 2);                 // output neuron index
    for (int j = 0; j < 4; ++j) {
        int k = g * 4 + j;
        bool kreal = ((k & 3) < 3) && (k < 12);   // real input-neuron slots
        int  i     = k - (k >> 2);                // input neuron index
        float v = 0.0f;
        if (l == 0) {
            if (orow && k < 2)        v = L * W1[o * 2 + k];
            else if (orow && k == 15) v = L * b1[o];
        } else if (l <= 19) {
            const float* W = Wmid + (l - 1) * 81;
            const float* b = bmid + (l - 1) * 9;
            if (orow) {
                if (kreal) {
                    v = L * W[o * 9 + i];
                } else if (k == 15) {             // bias slot (g3 j3)
                    float s = 0.0f;
                    for (int t = 0; t < H; ++t) s += W[o * 9 + t];
                    v = L * (b[o] - s);
                }
            }
        } else {  // l == 20: logits at rows 0,1
            if (row < 2) {
                if (kreal) {
                    v = W21[row * 9 + i];
                } else if (k == 15) {
                    float s = 0.0f;
                    for (int t = 0; t < H; ++t) s += W21[row * 9 + t];
                    v = b21[row] - s;
                }
            }
        }
        ws[l * 256 + lane * 4 + j] = (_Float16)v;
    }
}

// d (4 f32, d[3]==+0) -> fused next-layer B slots.  12 emitted, 3 trans:
//   p01 = pkrtz(d0,d1); r01 = pk_max; t01 = pk_min; e01 = pk_exp2 (2tr+pack)
//   w0  = pk_fma(r01, ln2, e01)                    [s(d0), s(d1)]
//   r2 = fmaxf(d2,0); t2 = fminf(d2,0); e2 = exp2f(t2) (1 tr)
//   w1  = pkrtz(fmaf(r2, ln2, e2), 1.0f)           [s(d2), 1.0h bias-act]
__device__ __forceinline__ void act(float4v d, unsigned &w0, unsigned &w1) {
    const h2 Z    = {(_Float16)0.f, (_Float16)0.f};
    const h2 LN2H = {(_Float16)0.6931471805599453f, (_Float16)0.6931471805599453f};
    h2 p01 = __builtin_bit_cast(h2, __builtin_amdgcn_cvt_pkrtz(d[0], d[1]));
    h2 r01 = __builtin_elementwise_max(p01, Z);
    h2 t01 = __builtin_elementwise_min(p01, Z);
    h2 e01 = __builtin_elementwise_exp2(t01);          // 2x v_exp_f16 + pack
    h2 s01 = __builtin_elementwise_fma(r01, LN2H, e01);
    w0 = __builtin_bit_cast(unsigned, s01);
    float r2 = fmaxf(d[2], 0.0f);
    float t2 = fminf(d[2], 0.0f);
    float e2 = __builtin_amdgcn_exp2f(t2);             // 1x v_exp_f32
    float s2 = fmaf(r2, 0.6931471805599453f, e2);
    w1 = __builtin_bit_cast(unsigned, __builtin_amdgcn_cvt_pkrtz(s2, 1.0f));
}

__device__ __forceinline__ float bperm(int byte_idx, float v) {
    return __builtin_bit_cast(float,
        __builtin_amdgcn_ds_bpermute(byte_idx, __builtin_bit_cast(int, v)));
}

// Wave-batched log-softmax + store for 4 tiles (dd[0..3] -> tiles gbase..+3).
__device__ __forceinline__ void softmax4(const float4v* dd, int gbase,
                                         int lane, int grp,
                                         float* __restrict__ out) {
    const float NLOG2E = -1.4426950408889634f;
    const float LN2f   = 0.6931471805599453f;
    const int bidx = (lane & 15) << 2;
    float a0 = bperm(bidx, dd[0][0]), a1 = bperm(bidx, dd[0][1]);
    float b0 = bperm(bidx, dd[1][0]), b1 = bperm(bidx, dd[1][1]);
    float c0 = bperm(bidx, dd[2][0]), c1 = bperm(bidx, dd[2][1]);
    float d0 = bperm(bidx, dd[3][0]), d1 = bperm(bidx, dd[3][1]);
    float l0 = (grp == 0) ? a0 : (grp == 1) ? b0 : (grp == 2) ? c0 : d0;
    float l1 = (grp == 0) ? a1 : (grp == 1) ? b1 : (grp == 2) ? c1 : d1;
    float mx  = fmaxf(l0, l1);
    float ad  = fabsf(l0 - l1);
    float e   = __builtin_amdgcn_exp2f(NLOG2E * ad);
    float lg  = __builtin_amdgcn_logf(1.0f + e);     // log2(1+e)
    float lse = fmaf(LN2f, lg, mx);
    ((float2*)out)[(gbase << 4) + lane] = make_float2(l0 - lse, l1 - lse);
}

__global__ __launch_bounds__(BLK, 4) void mlp_mfma(const float* __restrict__ x,
                                                   const _Float16* __restrict__ ws,
                                                   float* __restrict__ out) {
    const int lane  = threadIdx.x;        // single wave per block
    const int grp   = lane >> 4;
    const int col   = lane & 15;
    const int tile0 = blockIdx.x * TPW;   // < 131072, 32-bit safe

    const half4v* wsv = (const half4v*)ws;
    const unsigned bias_u1 = (grp == 3) ? 0x3C000000u : 0u;  // 1.0h @ j3 (k=15)
    const float4v ZV = {0.f, 0.f, 0.f, 0.f};

    // Load + pre-pack ALL 16 x fragments at wave start (1 VGPR each).
    // Layer-0 A cols k=4g,4g+1 are zero for g>0; x finite -> no mask needed.
    unsigned xb[TPW];
    #pragma unroll
    for (int k = 0; k < TPW; ++k) {
        float2 xv = ((const float2*)x)[((tile0 + k) << 4) + col];
        xb[k] = __builtin_bit_cast(unsigned,
                    __builtin_amdgcn_cvt_pkrtz(xv.x, xv.y));
    }

    #pragma unroll
    for (int pass = 0; pass < NPS; ++pass) {
        unsigned w0[NCH], w1[NCH];
        #pragma unroll
        for (int k = 0; k < NCH; ++k) {
            w0[k] = xb[pass * NCH + k];
            w1[k] = bias_u1;
        }

        // 21-layer chain, NCH independent chains in flight.
        float4v dd[NCH];
        #pragma unroll
        for (int l = 0; l < NL; ++l) {
            half4v A = wsv[l * 64 + lane];
            #pragma unroll
            for (int k = 0; k < NCH; ++k) {
                uint2v u = {w0[k], w1[k]};
                dd[k] = __builtin_amdgcn_mfma_f32_16x16x16f16(
                            A, __builtin_bit_cast(half4v, u), ZV, 0, 0, 0);
            }
            if (l < NL - 1) {
                #pragma unroll
                for (int k = 0; k < NCH; ++k)
                    act(dd[k], w0[k], w1[k]);
            }
        }

        softmax4(dd, tile0 + pass * NCH, lane, grp, out);
    }
}

extern "C" void kernel_launch(void* const* d_in, const int* in_sizes, int n_in,
                              void* d_out, int out_size, void* d_ws, size_t ws_size,
                              hipStream_t stream) {
    const float* x    = (const float*)d_in[0];
    const float* W1   = (const float*)d_in[1];
    const float* b1   = (const float*)d_in[2];
    const float* Wmid = (const float*)d_in[3];
    const float* bmid = (const float*)d_in[4];
    const float* W21  = (const float*)d_in[5];
    const float* b21  = (const float*)d_in[6];
    float* out = (float*)d_out;
    _Float16* ws = (_Float16*)d_ws;   // 21*256 halves = 10.75 KB

    build_frags<<<NL, 64, 0, stream>>>(W1, b1, Wmid, bmid, W21, b21, ws);

    const int nrows = in_sizes[0] / 2;           // 2097152
    const int tiles = nrows / 16;                // 131072
    const int blocks = tiles / TPW;              // 8192 single-wave blocks
    mlp_mfma<<<blocks, BLK, 0, stream>>>(x, ws, out);
}